// Round 11
// baseline (231.587 us; speedup 1.0000x reference)
//
#include <hip/hip_runtime.h>
#include <hip/hip_bf16.h>

#define DD 256
#define KC 1024
#define NT 32     // 32 tiles of 32 codes

typedef __attribute__((ext_vector_type(4))) float f32x4;
typedef __attribute__((ext_vector_type(8))) short bf16x8;

// Raw barrier: LDS ordering only (T4). Global stores/prefetch stay in flight.
#define BAR() do { \
    asm volatile("s_waitcnt lgkmcnt(0)" ::: "memory"); \
    __builtin_amdgcn_s_barrier(); \
    __builtin_amdgcn_sched_barrier(0); \
} while (0)

static __device__ __forceinline__ short f2bf(float f) {
    union { float f; unsigned u; } v; v.f = f;
    unsigned u = v.u;
    unsigned r = u + 0x7fffu + ((u >> 16) & 1u);
    return (short)(r >> 16);
}
static __device__ __forceinline__ float bf2f(short s) {
    union { unsigned u; float f; } v;
    v.u = ((unsigned)(unsigned short)s) << 16;
    return v.f;
}
static __device__ __forceinline__ unsigned pk2(float a, float b) {
    return (unsigned)(unsigned short)f2bf(a) |
           ((unsigned)(unsigned short)f2bf(b) << 16);
}

// ---------------------------------------------------------------------------
// prep: W fp32 [1024][256] -> wbf bf16 [1024][256], wtbf bf16 [256][1024],
//       wsq[k] = sum_d W[k][d]^2 / 256
// ---------------------------------------------------------------------------
__global__ void prep_kernel(const float* __restrict__ w, short* __restrict__ wbf,
                            short* __restrict__ wtbf, float* __restrict__ wsq) {
    const int cod = blockIdx.x;
    const int d   = threadIdx.x;           // 256 threads
    float v = w[cod * DD + d];
    short b = f2bf(v);
    wbf[cod * DD + d] = b;
    wtbf[d * KC + cod] = b;
    float s = v * v;
    #pragma unroll
    for (int m = 32; m >= 1; m >>= 1) s += __shfl_xor(s, m, 64);
    __shared__ float ps[4];
    const int wave = threadIdx.x >> 6, lane = threadIdx.x & 63;
    if (lane == 0) ps[wave] = s;
    __syncthreads();
    if (threadIdx.x == 0) {
        wsq[cod] = (ps[0] + ps[1] + ps[2] + ps[3]) * (1.0f / (float)DD);
    }
}

// ---------------------------------------------------------------------------
// Fused kernel, 64 rows/block, 512 thr (8 waves). R10 structure with the
// qdist store path restored to full-line vectorized stores (R9 style):
// q is written bf16 to et_, and AFTER the tile barrier each thread reads
// 8 B from et_ and stores one f32x4 (128 B/row per wave, no partial-line
// RMW — R10's scalar stores caused +128 MB FETCH / +267 MB WRITE).
// ---------------------------------------------------------------------------
__global__ __launch_bounds__(512, 4) void fused_kernel(
    const float* __restrict__ x, const short* __restrict__ wbf,
    const short* __restrict__ wtbf, const float* __restrict__ wsq,
    float* __restrict__ qdist, float* __restrict__ quant)
{
    __shared__ short wt_[2][32 * DD];     // 16 KB each: [code][256 d], swizzled
    __shared__ short wtT_[2][128 * 64];   // 16 KB each: superrow layout, swizzled
    __shared__ short et_[2][64 * 36];     // 4.6 KB each: q bf16 [row][32+4pad]
    __shared__ float red_[2][64];
    __shared__ float invs_[64];

    const int t   = threadIdx.x;
    const int w   = t >> 6, l = t & 63;
    const int lhi = l >> 4, llo = l & 15;
    const int rg  = w >> 1, cg = w & 1;
    const long rowbase = (long)blockIdx.x * 64;

    // staging thread identities
    const int sc  = t >> 4;              // wt: code 0..31
    const int sg0 = (t & 15) * 2;        // wt: first granule (even)
    const int sd  = t >> 1;              // wtT: d 0..255
    const int sg2 = (t & 1) * 2;         // wtT: granule pair in subrow
    const int ssr = sd >> 1;             // superrow
    const int shb = (sd & 1) * 4;

    bf16x8 wpf0, wpf1;
    float wscur, wsnext;

    // ---- issue wt tile0 loads ----
    { const short* p = wbf + (size_t)sc * DD + sg0 * 8;
      wpf0 = *(const bf16x8*)p; wpf1 = *(const bf16x8*)(p + 8); }

    // ---- x fragments (registers, pass-1 only) ----
    bf16x8 xa[8];
    {
        const float* xr = x + (rowbase + rg * 16 + llo) * DD + lhi * 8;
        #pragma unroll
        for (int kk = 0; kk < 8; kk++) {
            f32x4 v0 = *(const f32x4*)(xr + kk * 32);
            f32x4 v1 = *(const f32x4*)(xr + kk * 32 + 4);
            bf16x8 b;
            b[0]=f2bf(v0[0]); b[1]=f2bf(v0[1]); b[2]=f2bf(v0[2]); b[3]=f2bf(v0[3]);
            b[4]=f2bf(v1[0]); b[5]=f2bf(v1[1]); b[6]=f2bf(v1[2]); b[7]=f2bf(v1[3]);
            xa[kk] = b;
        }
    }

    // ---- stage wt tile0; load wt tile1; wsq ----
    *(bf16x8*)((char*)wt_[0] + sc*512 + (((sg0    ) ^ (sc&7)) << 4)) = wpf0;
    *(bf16x8*)((char*)wt_[0] + sc*512 + (((sg0 + 1) ^ (sc&7)) << 4)) = wpf1;
    { const short* p = wbf + (size_t)(32 + sc) * DD + sg0 * 8;
      wpf0 = *(const bf16x8*)p; wpf1 = *(const bf16x8*)(p + 8); }
    wscur  = wsq[cg * 16 + llo];
    wsnext = wsq[32 + cg * 16 + llo];

    const int  mycode = cg * 16 + llo;
    const int  cswz   = mycode & 7;
    char* const wtb0  = (char*)wt_[0] + mycode * 512;
    char* const wtb1  = (char*)wt_[1] + mycode * 512;

    float rs[4] = {0.f, 0.f, 0.f, 0.f};
    unsigned epk[NT][2];                 // packed bf16 e, fully unrolled access

    // =================== PASS 1: scores -> e in registers ===================
    #pragma unroll
    for (int i = 0; i < NT; i++) {
        BAR();
        if (i < NT - 1) {               // stage tile i+1 -> wt[(i+1)&1]
            char* wb = (char*)wt_[(i + 1) & 1] + sc * 512;
            *(bf16x8*)(wb + (((sg0    ) ^ (sc&7)) << 4)) = wpf0;
            *(bf16x8*)(wb + (((sg0 + 1) ^ (sc&7)) << 4)) = wpf1;
        }
        if (i < NT - 2) {               // load tile i+2
            const short* p = wbf + (size_t)((i + 2) * 32 + sc) * DD + sg0 * 8;
            wpf0 = *(const bf16x8*)p; wpf1 = *(const bf16x8*)(p + 8);
        }
        char* wb2 = (i & 1) ? wtb1 : wtb0;
        f32x4 sacc = {0.f, 0.f, 0.f, 0.f};
        #pragma unroll
        for (int kk = 0; kk < 8; kk++) {
            bf16x8 bb = *(const bf16x8*)(wb2 + (((kk * 4 + lhi) ^ cswz) << 4));
            sacc = __builtin_amdgcn_mfma_f32_16x16x32_bf16(xa[kk], bb, sacc, 0, 0, 0);
        }
        float e0 = __expf(sacc[0] * (1.0f / 128.0f) - wscur);
        float e1 = __expf(sacc[1] * (1.0f / 128.0f) - wscur);
        float e2 = __expf(sacc[2] * (1.0f / 128.0f) - wscur);
        float e3 = __expf(sacc[3] * (1.0f / 128.0f) - wscur);
        rs[0] += e0; rs[1] += e1; rs[2] += e2; rs[3] += e3;
        epk[i][0] = pk2(e0, e1);
        epk[i][1] = pk2(e2, e3);
        wscur = wsnext;
        if (i < NT - 2) wsnext = wsq[(i + 2) * 32 + cg * 16 + llo];
    }

    // ---- issue wtT tile0 loads early (cover under reduction) ----
    bf16x8 tpf0, tpf1;
    { const short* p = wtbf + (size_t)sd * KC + sg2 * 8;
      tpf0 = *(const bf16x8*)p; tpf1 = *(const bf16x8*)(p + 8); }

    // ---- rowsum reduce -> invs ----
    #pragma unroll
    for (int m = 1; m <= 8; m <<= 1)
        #pragma unroll
        for (int r = 0; r < 4; r++) rs[r] += __shfl_xor(rs[r], m, 64);
    if (llo == 0) {
        #pragma unroll
        for (int r = 0; r < 4; r++) red_[cg][rg * 16 + lhi * 4 + r] = rs[r];
    }
    __syncthreads();
    if (t < 64) invs_[t] = 1.0f / (red_[0][t] + red_[1][t]);
    __syncthreads();

    float inv4[4];
    #pragma unroll
    for (int r = 0; r < 4; r++) inv4[r] = invs_[rg * 16 + lhi * 4 + r];

    f32x4 uacc[4][2];   // transposed PV: D[d-subtile][row-subtile]
    #pragma unroll
    for (int a = 0; a < 4; a++)
        #pragma unroll
        for (int b = 0; b < 2; b++) uacc[a][b] = (f32x4){0.f, 0.f, 0.f, 0.f};

    float* qbase = qdist + rowbase * KC;
    const int myrow0 = rg * 16 + lhi * 4;
    const int qrow = t >> 3, c4 = (t & 7) * 4;   // qdist store identity

    // =================== PASS 2: PV + outputs (1 barrier/tile) ==============
    #pragma unroll
    for (int i = 0; i < NT; i++) {
        const int b = i & 1;
        // q values for tile i (from registers)
        float q0 = bf2f((short)(epk[i][0] & 0xffff)) * inv4[0];
        float q1 = bf2f((short)(epk[i][0] >> 16))    * inv4[1];
        float q2 = bf2f((short)(epk[i][1] & 0xffff)) * inv4[2];
        float q3 = bf2f((short)(epk[i][1] >> 16))    * inv4[3];
        // et write (stride 36 shorts = 72 B)
        et_[b][(myrow0 + 0) * 36 + mycode] = f2bf(q0);
        et_[b][(myrow0 + 1) * 36 + mycode] = f2bf(q1);
        et_[b][(myrow0 + 2) * 36 + mycode] = f2bf(q2);
        et_[b][(myrow0 + 3) * 36 + mycode] = f2bf(q3);
        // stage wtT tile i -> wtT[b]
        {
            char* tb = (char*)wtT_[b] + ssr * 128;
            *(bf16x8*)(tb + (((shb + sg2    ) ^ (ssr & 7)) << 4)) = tpf0;
            *(bf16x8*)(tb + (((shb + sg2 + 1) ^ (ssr & 7)) << 4)) = tpf1;
        }
        if (i < NT - 1) {               // load wtT tile i+1
            const short* p = wtbf + (size_t)sd * KC + (i + 1) * 32 + sg2 * 8;
            tpf0 = *(const bf16x8*)p; tpf1 = *(const bf16x8*)(p + 8);
        }
        BAR();
        // qdist store, full-line vectorized: 4 bf16 from et_ -> one f32x4
        {
            const char* ep = (const char*)et_[b] + qrow * 72 + c4 * 2;
            unsigned u0 = *(const unsigned*)ep;
            unsigned u1 = *(const unsigned*)(ep + 4);
            f32x4 o;
            o[0] = bf2f((short)(u0 & 0xffff)); o[1] = bf2f((short)(u0 >> 16));
            o[2] = bf2f((short)(u1 & 0xffff)); o[3] = bf2f((short)(u1 >> 16));
            *(f32x4*)(qbase + (size_t)qrow * KC + (size_t)i * 32 + c4) = o;
        }
        // PV from et_[b] + wtT_[b]
        bf16x8 bb0, bb1;
        {
            const int d0 = w * 32 + llo;
            bb0 = *(const bf16x8*)((char*)wtT_[b] + (d0 >> 1) * 128 +
                    (((((d0 & 1) << 2) + lhi) ^ ((d0 >> 1) & 7)) << 4));
            const int d1 = w * 32 + 16 + llo;
            bb1 = *(const bf16x8*)((char*)wtT_[b] + (d1 >> 1) * 128 +
                    (((((d1 & 1) << 2) + lhi) ^ ((d1 >> 1) & 7)) << 4));
        }
        #pragma unroll
        for (int rowg = 0; rowg < 4; rowg++) {
            bf16x8 aa = *(const bf16x8*)((char*)et_[b] + (rowg * 16 + llo) * 72 + lhi * 16);
            uacc[rowg][0] = __builtin_amdgcn_mfma_f32_16x16x32_bf16(bb0, aa, uacc[rowg][0], 0, 0, 0);
            uacc[rowg][1] = __builtin_amdgcn_mfma_f32_16x16x32_bf16(bb1, aa, uacc[rowg][1], 0, 0, 0);
        }
    }

    // quant stores: uacc[rowg][dg] = D[d][row] -> f32x4 along d (R9-verified map)
    #pragma unroll
    for (int rowg = 0; rowg < 4; rowg++)
        #pragma unroll
        for (int dg = 0; dg < 2; dg++)
            *(f32x4*)(quant + (rowbase + rowg * 16 + llo) * DD + w * 32 + dg * 16 + lhi * 4)
                = uacc[rowg][dg];
}

// ---------------------------------------------------------------------------
extern "C" void kernel_launch(void* const* d_in, const int* in_sizes, int n_in,
                              void* d_out, int out_size, void* d_ws, size_t ws_size,
                              hipStream_t stream) {
    const float* x = (const float*)d_in[0];
    const float* w = (const float*)d_in[1];
    float* out = (float*)d_out;

    const int nrows = in_sizes[0] / DD;          // 65536
    float* quant = out;                          // [nrows][256]
    float* qdist = out + (size_t)nrows * DD;     // [nrows][1024]

    short* wbf  = (short*)d_ws;                  // 1024*256 bf16 = 512 KB
    short* wtbf = wbf + (size_t)KC * DD;         // 256*1024 bf16 = 512 KB
    float* wsq  = (float*)(wtbf + (size_t)DD * KC);  // 1024 fp32

    prep_kernel<<<KC, DD, 0, stream>>>(w, wbf, wtbf, wsq);
    fused_kernel<<<nrows / 64, 512, 0, stream>>>(x, wbf, wtbf, wsq, qdist, quant);
}

// Round 12
// 174.730 us; speedup vs baseline: 1.3254x; 1.3254x over previous
//
#include <hip/hip_runtime.h>
#include <hip/hip_bf16.h>

#define DD 256
#define KC 1024
#define NT 32     // 32 tiles of 32 codes

typedef __attribute__((ext_vector_type(4))) float f32x4;
typedef __attribute__((ext_vector_type(8))) short bf16x8;

// Raw barrier: LDS ordering only (T4). Global stores/prefetch stay in flight.
#define BAR() do { \
    asm volatile("s_waitcnt lgkmcnt(0)" ::: "memory"); \
    __builtin_amdgcn_s_barrier(); \
    __builtin_amdgcn_sched_barrier(0); \
} while (0)

static __device__ __forceinline__ short f2bf(float f) {
    union { float f; unsigned u; } v; v.f = f;
    unsigned u = v.u;
    unsigned r = u + 0x7fffu + ((u >> 16) & 1u);
    return (short)(r >> 16);
}
static __device__ __forceinline__ float bf2f(short s) {
    union { unsigned u; float f; } v;
    v.u = ((unsigned)(unsigned short)s) << 16;
    return v.f;
}
static __device__ __forceinline__ unsigned pk2(float a, float b) {
    return (unsigned)(unsigned short)f2bf(a) |
           ((unsigned)(unsigned short)f2bf(b) << 16);
}

// ---------------------------------------------------------------------------
// prep: W fp32 [1024][256] -> wbf bf16 [1024][256], wtbf bf16 [256][1024],
//       wsq[k] = sum_d W[k][d]^2 / 256
// ---------------------------------------------------------------------------
__global__ void prep_kernel(const float* __restrict__ w, short* __restrict__ wbf,
                            short* __restrict__ wtbf, float* __restrict__ wsq) {
    const int cod = blockIdx.x;
    const int d   = threadIdx.x;           // 256 threads
    float v = w[cod * DD + d];
    short b = f2bf(v);
    wbf[cod * DD + d] = b;
    wtbf[d * KC + cod] = b;
    float s = v * v;
    #pragma unroll
    for (int m = 32; m >= 1; m >>= 1) s += __shfl_xor(s, m, 64);
    __shared__ float ps[4];
    const int wave = threadIdx.x >> 6, lane = threadIdx.x & 63;
    if (lane == 0) ps[wave] = s;
    __syncthreads();
    if (threadIdx.x == 0) {
        wsq[cod] = (ps[0] + ps[1] + ps[2] + ps[3]) * (1.0f / (float)DD);
    }
}

// ---------------------------------------------------------------------------
// Fused kernel, 64 rows/block, 512 thr (8 waves). R11 structure with
// __launch_bounds__(512, 2): VGPR cap 256 so epk[32][2] (64 regs) stays in
// REGISTERS. R10/R11's (512,4) capped VGPR at 128 -> allocator spilled epk
// to scratch = ~268 MB write + ~130 MB fetch per replay (the WRITE_SIZE
// 650 MB mystery). 1 block/CU now; explicit prefetch covers latency.
// ---------------------------------------------------------------------------
__global__ __launch_bounds__(512, 2) void fused_kernel(
    const float* __restrict__ x, const short* __restrict__ wbf,
    const short* __restrict__ wtbf, const float* __restrict__ wsq,
    float* __restrict__ qdist, float* __restrict__ quant)
{
    __shared__ short wt_[2][32 * DD];     // 16 KB each: [code][256 d], swizzled
    __shared__ short wtT_[2][128 * 64];   // 16 KB each: superrow layout, swizzled
    __shared__ short et_[2][64 * 36];     // 4.6 KB each: q bf16 [row][32+4pad]
    __shared__ float red_[2][64];
    __shared__ float invs_[64];

    const int t   = threadIdx.x;
    const int w   = t >> 6, l = t & 63;
    const int lhi = l >> 4, llo = l & 15;
    const int rg  = w >> 1, cg = w & 1;
    const long rowbase = (long)blockIdx.x * 64;

    // staging thread identities
    const int sc  = t >> 4;              // wt: code 0..31
    const int sg0 = (t & 15) * 2;        // wt: first granule (even)
    const int sd  = t >> 1;              // wtT: d 0..255
    const int sg2 = (t & 1) * 2;         // wtT: granule pair in subrow
    const int ssr = sd >> 1;             // superrow
    const int shb = (sd & 1) * 4;

    bf16x8 wpf0, wpf1;
    float wscur, wsnext;

    // ---- issue wt tile0 loads ----
    { const short* p = wbf + (size_t)sc * DD + sg0 * 8;
      wpf0 = *(const bf16x8*)p; wpf1 = *(const bf16x8*)(p + 8); }

    // ---- x fragments (registers, pass-1 only) ----
    bf16x8 xa[8];
    {
        const float* xr = x + (rowbase + rg * 16 + llo) * DD + lhi * 8;
        #pragma unroll
        for (int kk = 0; kk < 8; kk++) {
            f32x4 v0 = *(const f32x4*)(xr + kk * 32);
            f32x4 v1 = *(const f32x4*)(xr + kk * 32 + 4);
            bf16x8 b;
            b[0]=f2bf(v0[0]); b[1]=f2bf(v0[1]); b[2]=f2bf(v0[2]); b[3]=f2bf(v0[3]);
            b[4]=f2bf(v1[0]); b[5]=f2bf(v1[1]); b[6]=f2bf(v1[2]); b[7]=f2bf(v1[3]);
            xa[kk] = b;
        }
    }

    // ---- stage wt tile0; load wt tile1; wsq ----
    *(bf16x8*)((char*)wt_[0] + sc*512 + (((sg0    ) ^ (sc&7)) << 4)) = wpf0;
    *(bf16x8*)((char*)wt_[0] + sc*512 + (((sg0 + 1) ^ (sc&7)) << 4)) = wpf1;
    { const short* p = wbf + (size_t)(32 + sc) * DD + sg0 * 8;
      wpf0 = *(const bf16x8*)p; wpf1 = *(const bf16x8*)(p + 8); }
    wscur  = wsq[cg * 16 + llo];
    wsnext = wsq[32 + cg * 16 + llo];

    const int  mycode = cg * 16 + llo;
    const int  cswz   = mycode & 7;
    char* const wtb0  = (char*)wt_[0] + mycode * 512;
    char* const wtb1  = (char*)wt_[1] + mycode * 512;

    float rs[4] = {0.f, 0.f, 0.f, 0.f};
    unsigned epk[NT][2];                 // packed bf16 e — MUST stay in VGPRs

    // =================== PASS 1: scores -> e in registers ===================
    #pragma unroll
    for (int i = 0; i < NT; i++) {
        BAR();
        if (i < NT - 1) {               // stage tile i+1 -> wt[(i+1)&1]
            char* wb = (char*)wt_[(i + 1) & 1] + sc * 512;
            *(bf16x8*)(wb + (((sg0    ) ^ (sc&7)) << 4)) = wpf0;
            *(bf16x8*)(wb + (((sg0 + 1) ^ (sc&7)) << 4)) = wpf1;
        }
        if (i < NT - 2) {               // load tile i+2
            const short* p = wbf + (size_t)((i + 2) * 32 + sc) * DD + sg0 * 8;
            wpf0 = *(const bf16x8*)p; wpf1 = *(const bf16x8*)(p + 8);
        }
        char* wb2 = (i & 1) ? wtb1 : wtb0;
        f32x4 sacc = {0.f, 0.f, 0.f, 0.f};
        #pragma unroll
        for (int kk = 0; kk < 8; kk++) {
            bf16x8 bb = *(const bf16x8*)(wb2 + (((kk * 4 + lhi) ^ cswz) << 4));
            sacc = __builtin_amdgcn_mfma_f32_16x16x32_bf16(xa[kk], bb, sacc, 0, 0, 0);
        }
        float e0 = __expf(sacc[0] * (1.0f / 128.0f) - wscur);
        float e1 = __expf(sacc[1] * (1.0f / 128.0f) - wscur);
        float e2 = __expf(sacc[2] * (1.0f / 128.0f) - wscur);
        float e3 = __expf(sacc[3] * (1.0f / 128.0f) - wscur);
        rs[0] += e0; rs[1] += e1; rs[2] += e2; rs[3] += e3;
        epk[i][0] = pk2(e0, e1);
        epk[i][1] = pk2(e2, e3);
        wscur = wsnext;
        if (i < NT - 2) wsnext = wsq[(i + 2) * 32 + cg * 16 + llo];
    }

    // ---- issue wtT tile0 loads early (cover under reduction) ----
    bf16x8 tpf0, tpf1;
    { const short* p = wtbf + (size_t)sd * KC + sg2 * 8;
      tpf0 = *(const bf16x8*)p; tpf1 = *(const bf16x8*)(p + 8); }

    // ---- rowsum reduce -> invs ----
    #pragma unroll
    for (int m = 1; m <= 8; m <<= 1)
        #pragma unroll
        for (int r = 0; r < 4; r++) rs[r] += __shfl_xor(rs[r], m, 64);
    if (llo == 0) {
        #pragma unroll
        for (int r = 0; r < 4; r++) red_[cg][rg * 16 + lhi * 4 + r] = rs[r];
    }
    __syncthreads();
    if (t < 64) invs_[t] = 1.0f / (red_[0][t] + red_[1][t]);
    __syncthreads();

    float inv4[4];
    #pragma unroll
    for (int r = 0; r < 4; r++) inv4[r] = invs_[rg * 16 + lhi * 4 + r];

    f32x4 uacc[4][2];   // transposed PV: D[d-subtile][row-subtile]
    #pragma unroll
    for (int a = 0; a < 4; a++)
        #pragma unroll
        for (int b = 0; b < 2; b++) uacc[a][b] = (f32x4){0.f, 0.f, 0.f, 0.f};

    float* qbase = qdist + rowbase * KC;
    const int myrow0 = rg * 16 + lhi * 4;
    const int qrow = t >> 3, c4 = (t & 7) * 4;   // qdist store identity

    // =================== PASS 2: PV + outputs (1 barrier/tile) ==============
    #pragma unroll
    for (int i = 0; i < NT; i++) {
        const int b = i & 1;
        // q values for tile i (from registers)
        float q0 = bf2f((short)(epk[i][0] & 0xffff)) * inv4[0];
        float q1 = bf2f((short)(epk[i][0] >> 16))    * inv4[1];
        float q2 = bf2f((short)(epk[i][1] & 0xffff)) * inv4[2];
        float q3 = bf2f((short)(epk[i][1] >> 16))    * inv4[3];
        // et write (stride 36 shorts = 72 B)
        et_[b][(myrow0 + 0) * 36 + mycode] = f2bf(q0);
        et_[b][(myrow0 + 1) * 36 + mycode] = f2bf(q1);
        et_[b][(myrow0 + 2) * 36 + mycode] = f2bf(q2);
        et_[b][(myrow0 + 3) * 36 + mycode] = f2bf(q3);
        // stage wtT tile i -> wtT[b]
        {
            char* tb = (char*)wtT_[b] + ssr * 128;
            *(bf16x8*)(tb + (((shb + sg2    ) ^ (ssr & 7)) << 4)) = tpf0;
            *(bf16x8*)(tb + (((shb + sg2 + 1) ^ (ssr & 7)) << 4)) = tpf1;
        }
        if (i < NT - 1) {               // load wtT tile i+1
            const short* p = wtbf + (size_t)sd * KC + (i + 1) * 32 + sg2 * 8;
            tpf0 = *(const bf16x8*)p; tpf1 = *(const bf16x8*)(p + 8);
        }
        BAR();
        // qdist store, full-line vectorized: 4 bf16 from et_ -> one f32x4
        {
            const char* ep = (const char*)et_[b] + qrow * 72 + c4 * 2;
            unsigned u0 = *(const unsigned*)ep;
            unsigned u1 = *(const unsigned*)(ep + 4);
            f32x4 o;
            o[0] = bf2f((short)(u0 & 0xffff)); o[1] = bf2f((short)(u0 >> 16));
            o[2] = bf2f((short)(u1 & 0xffff)); o[3] = bf2f((short)(u1 >> 16));
            *(f32x4*)(qbase + (size_t)qrow * KC + (size_t)i * 32 + c4) = o;
        }
        // PV from et_[b] + wtT_[b]
        bf16x8 bb0, bb1;
        {
            const int d0 = w * 32 + llo;
            bb0 = *(const bf16x8*)((char*)wtT_[b] + (d0 >> 1) * 128 +
                    (((((d0 & 1) << 2) + lhi) ^ ((d0 >> 1) & 7)) << 4));
            const int d1 = w * 32 + 16 + llo;
            bb1 = *(const bf16x8*)((char*)wtT_[b] + (d1 >> 1) * 128 +
                    (((((d1 & 1) << 2) + lhi) ^ ((d1 >> 1) & 7)) << 4));
        }
        #pragma unroll
        for (int rowg = 0; rowg < 4; rowg++) {
            bf16x8 aa = *(const bf16x8*)((char*)et_[b] + (rowg * 16 + llo) * 72 + lhi * 16);
            uacc[rowg][0] = __builtin_amdgcn_mfma_f32_16x16x32_bf16(bb0, aa, uacc[rowg][0], 0, 0, 0);
            uacc[rowg][1] = __builtin_amdgcn_mfma_f32_16x16x32_bf16(bb1, aa, uacc[rowg][1], 0, 0, 0);
        }
    }

    // quant stores: uacc[rowg][dg] = D[d][row] -> f32x4 along d (R9-verified map)
    #pragma unroll
    for (int rowg = 0; rowg < 4; rowg++)
        #pragma unroll
        for (int dg = 0; dg < 2; dg++)
            *(f32x4*)(quant + (rowbase + rowg * 16 + llo) * DD + w * 32 + dg * 16 + lhi * 4)
                = uacc[rowg][dg];
}

// ---------------------------------------------------------------------------
extern "C" void kernel_launch(void* const* d_in, const int* in_sizes, int n_in,
                              void* d_out, int out_size, void* d_ws, size_t ws_size,
                              hipStream_t stream) {
    const float* x = (const float*)d_in[0];
    const float* w = (const float*)d_in[1];
    float* out = (float*)d_out;

    const int nrows = in_sizes[0] / DD;          // 65536
    float* quant = out;                          // [nrows][256]
    float* qdist = out + (size_t)nrows * DD;     // [nrows][1024]

    short* wbf  = (short*)d_ws;                  // 1024*256 bf16 = 512 KB
    short* wtbf = wbf + (size_t)KC * DD;         // 256*1024 bf16 = 512 KB
    float* wsq  = (float*)(wtbf + (size_t)DD * KC);  // 1024 fp32

    prep_kernel<<<KC, DD, 0, stream>>>(w, wbf, wtbf, wsq);
    fused_kernel<<<nrows / 64, 512, 0, stream>>>(x, wbf, wtbf, wsq, qdist, quant);
}